// Round 7
// baseline (68.570 us; speedup 1.0000x reference)
//
#include <hip/hip_runtime.h>

#ifndef __has_builtin
#define __has_builtin(x) 0
#endif

__device__ __forceinline__ float fexp2(float x) {
#if __has_builtin(__builtin_amdgcn_exp2f)
    return __builtin_amdgcn_exp2f(x);   // v_exp_f32: 2^x
#else
    return exp2f(x);
#endif
}

__device__ __forceinline__ float fcos_rev(float r) {
#if __has_builtin(__builtin_amdgcn_cosf)
    return __builtin_amdgcn_cosf(r);    // v_cos_f32: cos(2*pi*r), r in revolutions
#else
    return __cosf(r * 6.283185307179586f);
#endif
}

typedef __attribute__((ext_vector_type(2))) float v2f;

// Packed FP32 (VOP3P, FeaturePackedFP32Ops — gfx90a+, present on gfx950).
// Two independent j-elements ride in one 64-bit VGPR pair; halves ladder instrs.
// VALIDATED CONFIG (R3, absmax 0.5): scalar setup -> explicit {lo,hi} pair
// construction -> pk_mul/pk_add asm ladder. Do NOT feed compiler-vectorized
// dataflow into these asm ops (R4/R5 both failed: half mis-pairing), and do
// NOT hand-write v_pk_fma_f32 (R4, absmax 2.4e31).
__device__ __forceinline__ v2f pk_mul(v2f a, v2f b) {
    v2f d;
    asm("v_pk_mul_f32 %0, %1, %2" : "=v"(d) : "v"(a), "v"(b));
    return d;
}
__device__ __forceinline__ v2f pk_add(v2f a, v2f b) {
    v2f d;
    asm("v_pk_add_f32 %0, %1, %2" : "=v"(d) : "v"(a), "v"(b));
    return d;
}

constexpr int NATOMS = 512;
constexpr int NP     = 16;

// eta=16, delta=0.26875, shifts s_p = 0.9 + p*delta, anchors s_4=1.975, s_12=4.125
// Gaussian ladder in base-2 domain (verified R1-R3, absmax 0.5 vs thr 2.52):
//   g_p = 2^(C t_p^2), C = -16*log2(e)
//   g_{p+1} = g_p * w,  w = 2^(A t + B) stepped by k2 = 2^(-A*delta)
//   g_{p-1} = g_p * v,  v = 2^(-A t + B) stepped by k2
//   A = 32*delta*log2(e) = 12.407177351645085, B = -16*delta^2*log2(e)
// Upper-anchor (p=12) factors: w_h = w_l * 2^(-A*2.15), v_h = v_l * 2^(+A*2.15)

// Scalar per-element setup: mask, cutoff cosine, anchor Gaussians, ladder factors.
__device__ __forceinline__ void setup_elem(float dv, float zv,
                                           float& gl, float& gh,
                                           float& wl, float& vl) {
    const float C   = -23.083120654223414f;
    const float A   = 12.407177351645085f;
    const float B   = -1.6672144566f;
    const float REV = 0.09615384615384616f;   // 1/(2*5.2), cos arg in revolutions

    bool  valid = (dv < 5.2f) && (dv != 0.0f);
    float fc    = fmaf(0.5f, fcos_rev(dv * REV), 0.5f);
    float we    = valid ? zv * fc : 0.0f;

    float tl = dv - 1.975f;                   // t_4
    float th = dv - 4.125f;                   // t_12
    gl = we * fexp2((C * tl) * tl);           // g_4 * we
    gh = we * fexp2((C * th) * th);           // g_12 * we
    wl = fexp2(fmaf(A, tl, B));               // w_4
    vl = fexp2(fmaf(-A, tl, B));              // v_4
}

// Packed ladder: processes a PAIR of elements per instruction.
__device__ __forceinline__ void ladder_pair(v2f* acc2, v2f GL, v2f GH,
                                            v2f WL, v2f VL,
                                            v2f K2, v2f CWH, v2f CVH) {
    v2f g, w, v;
    // lower half, anchor p=4
    acc2[4] = pk_add(acc2[4], GL);
    g = pk_mul(GL, WL); acc2[5] = pk_add(acc2[5], g); w = pk_mul(WL, K2);
    g = pk_mul(g,  w ); acc2[6] = pk_add(acc2[6], g); w = pk_mul(w,  K2);
    g = pk_mul(g,  w ); acc2[7] = pk_add(acc2[7], g);
    g = pk_mul(GL, VL); acc2[3] = pk_add(acc2[3], g); v = pk_mul(VL, K2);
    g = pk_mul(g,  v ); acc2[2] = pk_add(acc2[2], g); v = pk_mul(v,  K2);
    g = pk_mul(g,  v ); acc2[1] = pk_add(acc2[1], g); v = pk_mul(v,  K2);
    g = pk_mul(g,  v ); acc2[0] = pk_add(acc2[0], g);
    // upper half, anchor p=12
    v2f WH = pk_mul(WL, CWH);
    v2f VH = pk_mul(VL, CVH);
    acc2[12] = pk_add(acc2[12], GH);
    g = pk_mul(GH, WH); acc2[13] = pk_add(acc2[13], g); w = pk_mul(WH, K2);
    g = pk_mul(g,  w ); acc2[14] = pk_add(acc2[14], g); w = pk_mul(w,  K2);
    g = pk_mul(g,  w ); acc2[15] = pk_add(acc2[15], g);
    g = pk_mul(GH, VH); acc2[11] = pk_add(acc2[11], g); v = pk_mul(VH, K2);
    g = pk_mul(g,  v ); acc2[10] = pk_add(acc2[10], g); v = pk_mul(v,  K2);
    g = pk_mul(g,  v ); acc2[9]  = pk_add(acc2[9],  g); v = pk_mul(v,  K2);
    g = pk_mul(g,  v ); acc2[8]  = pk_add(acc2[8],  g);
}

__global__ __launch_bounds__(256, 4) void aev_radial_kernel(
        const float* __restrict__ d,   // (B, N, N)
        const float* __restrict__ z,   // (B, N)
        float* __restrict__ out)       // (B, N, NP)
{
    const int lane = threadIdx.x & 63;
    const int wave = threadIdx.x >> 6;
    const int row  = blockIdx.x * 4 + wave;      // row = b*N + i, in [0, 8192)
    const int b    = row >> 9;                   // N = 512

    const float4* __restrict__ dd = reinterpret_cast<const float4*>(d + (size_t)row * NATOMS);
    const float4* __restrict__ zz = reinterpret_cast<const float4*>(z + (size_t)b   * NATOMS);

    const float k2v  = fexp2(-3.3344289132f);    // 2^(-A*delta)
    const float cwhv = fexp2(-26.675431306f);    // 2^(-A*2.15)
    const float cvhv = fexp2( 26.675431306f);    // 2^(+A*2.15)
    const v2f K2  = {k2v,  k2v};
    const v2f CWH = {cwhv, cwhv};
    const v2f CVH = {cvhv, cvhv};

    v2f acc2[NP];
#pragma unroll
    for (int p = 0; p < NP; ++p) acc2[p] = (v2f){0.0f, 0.0f};

#pragma unroll
    for (int h = 0; h < 2; ++h) {
        float4 dv4 = dd[lane + 64 * h];
        float4 zv4 = zz[lane + 64 * h];
#pragma unroll
        for (int pr = 0; pr < 2; ++pr) {         // two pairs per float4
            float d0 = (&dv4.x)[2 * pr],     z0 = (&zv4.x)[2 * pr];
            float d1 = (&dv4.x)[2 * pr + 1], z1 = (&zv4.x)[2 * pr + 1];
            float gl0, gh0, wl0, vl0, gl1, gh1, wl1, vl1;
            setup_elem(d0, z0, gl0, gh0, wl0, vl0);
            setup_elem(d1, z1, gl1, gh1, wl1, vl1);
            v2f GL = {gl0, gl1}, GH = {gh0, gh1};
            v2f WL = {wl0, wl1}, VL = {vl0, vl1};
            ladder_pair(acc2, GL, GH, WL, VL, K2, CWH, CVH);
        }
    }

    // Collapse packed halves (independent partial sums over j) to scalar.
    float acc[NP];
#pragma unroll
    for (int p = 0; p < NP; ++p) acc[p] = acc2[p].x + acc2[p].y;

    // Lane-halving butterfly reduction (16 accs x 64 lanes -> 16 outputs)
    bool u;
    float r0[8];
    u = (lane & 1) != 0;
#pragma unroll
    for (int k = 0; k < 8; ++k) {
        float snd  = u ? acc[k] : acc[k + 8];
        float rcv  = __shfl_xor(snd, 1, 64);
        float kept = u ? acc[k + 8] : acc[k];
        r0[k] = kept + rcv;
    }
    float r1[4];
    u = (lane & 2) != 0;
#pragma unroll
    for (int k = 0; k < 4; ++k) {
        float snd  = u ? r0[k] : r0[k + 4];
        float rcv  = __shfl_xor(snd, 2, 64);
        float kept = u ? r0[k + 4] : r0[k];
        r1[k] = kept + rcv;
    }
    float r2[2];
    u = (lane & 4) != 0;
#pragma unroll
    for (int k = 0; k < 2; ++k) {
        float snd  = u ? r1[k] : r1[k + 2];
        float rcv  = __shfl_xor(snd, 4, 64);
        float kept = u ? r1[k + 2] : r1[k];
        r2[k] = kept + rcv;
    }
    float r3;
    u = (lane & 8) != 0;
    {
        float snd  = u ? r2[0] : r2[1];
        float rcv  = __shfl_xor(snd, 8, 64);
        float kept = u ? r2[1] : r2[0];
        r3 = kept + rcv;
    }
    r3 += __shfl_xor(r3, 16, 64);
    r3 += __shfl_xor(r3, 32, 64);

    // acc index held by this lane: bit-reversal of (lane & 15)
    int idx = ((lane & 1) << 3) | ((lane & 2) << 1) | ((lane & 4) >> 1) | ((lane & 8) >> 3);
    if (lane < 16) {
        out[(size_t)row * NP + idx] = r3;
    }
}

extern "C" void kernel_launch(void* const* d_in, const int* in_sizes, int n_in,
                              void* d_out, int out_size, void* d_ws, size_t ws_size,
                              hipStream_t stream) {
    const float* d  = (const float*)d_in[0];   // (16, 512, 512) fp32
    const float* z  = (const float*)d_in[1];   // (16, 512) fp32
    float* out      = (float*)d_out;           // (16, 512, 16) fp32

    aev_radial_kernel<<<dim3(2048), dim3(256), 0, stream>>>(d, z, out);
}